// Round 10
// baseline (1227.012 us; speedup 1.0000x reference)
//
#include <hip/hip_runtime.h>
#include <math.h>

#define NB 64
#define CO 512
#define NGATES 2048
#define INDIM 768
#define KTOT 1280
#define IMG 256
#define GS 16
#define EPSF 1e-4f
#define NCHUNK 8
#define CHUNK 160   // KTOT / NCHUNK

#define FMA4(A,S,V) {(A).x+=(S)*(V).x;(A).y+=(S)*(V).y;(A).z+=(S)*(V).z;(A).w+=(S)*(V).w;}
#define RLF(x,i) __uint_as_float(__builtin_amdgcn_readlane(__float_as_uint(x),(i)))

__device__ __forceinline__ float sigmoidf_(float x){ return 1.0f/(1.0f+expf(-x)); }

__device__ __forceinline__ float waveReduceSum(float v){
  #pragma unroll
  for (int off=32; off>0; off>>=1) v += __shfl_down(v, off, 64);
  return v;
}

// out[c][r] = in[r][c]; rows, cols multiples of 32
__global__ __launch_bounds__(256) void transpose_k(const float* __restrict__ in,
                                                   float* __restrict__ out,
                                                   int rows, int cols){
  __shared__ float tile[32][33];
  int bx = blockIdx.x*32, by = blockIdx.y*32;
  int tx = threadIdx.x, ty = threadIdx.y;
  #pragma unroll
  for (int i=ty;i<32;i+=8)
    tile[i][tx] = in[(size_t)(by+i)*cols + bx+tx];
  __syncthreads();
  #pragma unroll
  for (int i=ty;i<32;i+=8)
    out[(size_t)(bx+i)*rows + by+tx] = tile[tx][i];
}

// ===== r8 kernels, verbatim =====
__global__ __launch_bounds__(512) void extlstm4_k(
    const float* __restrict__ imgs, int t,
    const float* __restrict__ partT,
    const float* __restrict__ b_ih, const float* __restrict__ b_hh,
    const float* __restrict__ Wg,   const float* __restrict__ bg,
    float* __restrict__ cbuf, float* __restrict__ xhT)
{
  __shared__ float hs[CO];
  __shared__ float gp[3];
  __shared__ float wred[8][4];
  __shared__ float prt[2][GS][4];
  __shared__ float rowinv[2][GS];
  __shared__ float fhT[256][20];
  __shared__ float fws[GS][260];
  __shared__ float g1[4][GS][260];
  __shared__ float g2[256][2];

  const int bc = blockIdx.x;
  const int b = bc/3, c = bc%3;
  const int t0 = threadIdx.x;
  const int q = t0>>6, lane = t0&63;

  if (t == 0){
    if (t0 < 256){ hs[t0]=0.f; hs[t0+256]=0.f; }
    if (c == 0) xhT[(size_t)(INDIM+t0)*NB + b] = 0.f;
  } else {
    const int u = t0;
    float gi=0.f,gf=0.f,gc=0.f,go=0.f;
    #pragma unroll
    for (int s2=0;s2<NCHUNK;s2++){
      const float* p = partT + ((size_t)s2*NB + b)*NGATES;
      gi += p[u]; gf += p[512+u]; gc += p[1024+u]; go += p[1536+u];
    }
    gi += b_ih[u]      + b_hh[u];
    gf += b_ih[512+u]  + b_hh[512+u];
    gc += b_ih[1024+u] + b_hh[1024+u];
    go += b_ih[1536+u] + b_hh[1536+u];
    float cold = (t==1) ? 0.f : cbuf[(size_t)((t-1)&1)*NB*CO + (size_t)b*CO + u];
    float cnew = sigmoidf_(gf)*cold + sigmoidf_(gi)*tanhf(gc);
    float hnew = sigmoidf_(go)*tanhf(cnew);
    hs[u] = hnew;
    if (c == 0){
      cbuf[(size_t)(t&1)*NB*CO + (size_t)b*CO + u] = cnew;
      xhT[(size_t)(INDIM+u)*NB + b] = hnew;
    }
  }
  __syncthreads();

  {
    float hval = hs[t0];
    float p0 = Wg[0*CO+t0]*hval;
    float p1 = Wg[1*CO+t0]*hval;
    float p2 = Wg[2*CO+t0]*hval;
    p0 = waveReduceSum(p0); p1 = waveReduceSum(p1); p2 = waveReduceSum(p2);
    if (lane==0){ wred[q][0]=p0; wred[q][1]=p1; wred[q][2]=p2; }
    __syncthreads();
    if (t0 < 3){
      float s = 0.f;
      #pragma unroll
      for (int w8=0; w8<8; w8++) s += wred[w8][t0];
      gp[t0] = tanhf(s + bg[t0]);
    }
    __syncthreads();
  }

  {
    float delta = gp[2];
    float dabs  = fabsf(delta);
    float deltas = ((float)IMG/(float)GS) * (1.0f - dabs);
    float gamma  = expf(1.0f - 2.0f*dabs);
    float inv_g  = 1.0f/gamma;
    float pref   = 1.0f/(3.14159265358979f*gamma);
    const int fb = t0 >> 8;
    const int p  = t0 & 255;
    const int wid = q & 3;
    float fi = (float)p;
    float fx[GS];
    float centers = 255.0f*0.5f*(gp[fb]+1.0f);
    #pragma unroll
    for (int g=0; g<GS; g++){
      float mu = centers + deltas*((float)g - 7.5f);
      float d  = (fi - mu)*inv_g;
      fx[g] = pref/(1.0f + d*d);
    }
    #pragma unroll
    for (int g=0; g<GS; g++){
      float sv = waveReduceSum(fx[g]);
      if (lane==0) prt[fb][g][wid]=sv;
    }
    __syncthreads();
    if (t0 < 32){
      int f2 = t0 >> 4, g = t0 & 15;
      rowinv[f2][g] = 1.0f/((((prt[f2][g][0]+prt[f2][g][1])+prt[f2][g][2])+prt[f2][g][3]) + EPSF);
    }
    __syncthreads();
    if (fb==0){
      #pragma unroll
      for (int g=0; g<GS; g++) fhT[p][g] = fx[g]*rowinv[0][g];
    } else {
      #pragma unroll
      for (int g=0; g<GS; g++) fws[g][p] = fx[g]*rowinv[1][g];
    }
    __syncthreads();
  }

  {
    const float4* img4 = (const float4*)(imgs
        + (((size_t)b*2 + (t&1))*3 + c)*((size_t)IMG*IMG));
    float4 acc[GS];
    #pragma unroll
    for (int g=0; g<GS; g++){ acc[g].x=0.f; acc[g].y=0.f; acc[g].z=0.f; acc[g].w=0.f; }
    const int row0 = q*32;
    #pragma unroll 8
    for (int i=0; i<32; i++){
      const int row = row0 + i;
      float4 v = img4[(size_t)row*64 + lane];
      const float4* fq = (const float4*)&fhT[row][0];
      float4 f0=fq[0], f1=fq[1], f2=fq[2], f3=fq[3];
      FMA4(acc[0], f0.x, v); FMA4(acc[1], f0.y, v); FMA4(acc[2], f0.z, v); FMA4(acc[3], f0.w, v);
      FMA4(acc[4], f1.x, v); FMA4(acc[5], f1.y, v); FMA4(acc[6], f1.z, v); FMA4(acc[7], f1.w, v);
      FMA4(acc[8], f2.x, v); FMA4(acc[9], f2.y, v); FMA4(acc[10],f2.z, v); FMA4(acc[11],f2.w, v);
      FMA4(acc[12],f3.x, v); FMA4(acc[13],f3.y, v); FMA4(acc[14],f3.z, v); FMA4(acc[15],f3.w, v);
    }
    if (q < 4){
      #pragma unroll
      for (int g=0; g<GS; g++) *(float4*)&g1[q][g][lane*4] = acc[g];
    }
    __syncthreads();
    if (q >= 4){
      #pragma unroll
      for (int g=0; g<GS; g++){
        float4 o = *(float4*)&g1[q-4][g][lane*4];
        o.x+=acc[g].x; o.y+=acc[g].y; o.z+=acc[g].z; o.w+=acc[g].w;
        *(float4*)&g1[q-4][g][lane*4] = o;
      }
    }
    __syncthreads();
    {
      #pragma unroll
      for (int gi2=0; gi2<2; gi2++){
        int g = q*2 + gi2;
        float4 s0 = *(float4*)&g1[0][g][lane*4];
        float4 s1 = *(float4*)&g1[1][g][lane*4];
        float4 s2 = *(float4*)&g1[2][g][lane*4];
        float4 s3 = *(float4*)&g1[3][g][lane*4];
        s0.x = ((s0.x+s1.x)+s2.x)+s3.x;
        s0.y = ((s0.y+s1.y)+s2.y)+s3.y;
        s0.z = ((s0.z+s1.z)+s2.z)+s3.z;
        s0.w = ((s0.w+s1.w)+s2.w)+s3.w;
        *(float4*)&g1[0][g][lane*4] = s0;
      }
    }
    __syncthreads();
  }

  {
    int h2 = q >> 2;
    int o  = (q & 3)*64 + lane;
    int gg = o >> 4, kk = o & 15;
    const float4* grow = (const float4*)&g1[0][gg][h2*128];
    const float4* frow = (const float4*)&fws[kk][h2*128];
    float s = 0.f;
    #pragma unroll 8
    for (int j=0; j<32; j++){
      float4 gv = grow[j], fv = frow[j];
      s += gv.x*fv.x; s += gv.y*fv.y; s += gv.z*fv.z; s += gv.w*fv.w;
    }
    g2[o][h2] = s;
    __syncthreads();
    if (t0 < 256)
      xhT[(size_t)(c*256 + t0)*NB + b] = g2[t0][0] + g2[t0][1];
  }
}

__global__ __launch_bounds__(256) void gates5_k(
    const float* __restrict__ Wcat, const float* __restrict__ xhT,
    float* __restrict__ partT)
{
  __shared__ float tile[32][65];
  int s  = blockIdx.x & (NCHUNK-1);
  int rt = blockIdx.x >> 3;
  int wave = threadIdx.x >> 6, lane = threadIdx.x & 63;
  int r0 = rt*32 + wave*8;
  int c0 = s*CHUNK;
  const float* ap = xhT + (size_t)c0*NB + lane;
  const float* wp = Wcat + (size_t)c0*NGATES + r0;
  float acc[8];
  #pragma unroll
  for (int i=0;i<8;i++) acc[i]=0.f;
  #pragma unroll 4
  for (int k=0;k<CHUNK;k++){
    float a = ap[(size_t)k*NB];
    const float4* wr = (const float4*)(wp + (size_t)k*NGATES);
    float4 w0=wr[0], w1=wr[1];
    acc[0]+=w0.x*a; acc[1]+=w0.y*a; acc[2]+=w0.z*a; acc[3]+=w0.w*a;
    acc[4]+=w1.x*a; acc[5]+=w1.y*a; acc[6]+=w1.z*a; acc[7]+=w1.w*a;
  }
  #pragma unroll
  for (int i=0;i<8;i++) tile[wave*8+i][lane] = acc[i];
  __syncthreads();
  int b = threadIdx.x >> 2, qq = threadIdx.x & 3;
  float* dst = partT + ((size_t)s*NB + b)*NGATES + rt*32 + qq*8;
  float4 v0, v1;
  v0.x=tile[qq*8+0][b]; v0.y=tile[qq*8+1][b]; v0.z=tile[qq*8+2][b]; v0.w=tile[qq*8+3][b];
  v1.x=tile[qq*8+4][b]; v1.y=tile[qq*8+5][b]; v1.z=tile[qq*8+6][b]; v1.w=tile[qq*8+7][b];
  *(float4*)dst = v0;
  *(float4*)(dst+4) = v1;
}

__global__ __launch_bounds__(512) void final_k(
    const float* __restrict__ partT,
    const float* __restrict__ b_ih, const float* __restrict__ b_hh,
    const float* __restrict__ cbuf, float* __restrict__ out)
{
  int b = blockIdx.x, u = threadIdx.x;
  float gi=0.f, gf=0.f, gc=0.f, go=0.f;
  #pragma unroll
  for (int s2=0; s2<NCHUNK; s2++){
    const float* p = partT + ((size_t)s2*NB + b)*NGATES;
    gi += p[u]; gf += p[512+u]; gc += p[1024+u]; go += p[1536+u];
  }
  gi += b_ih[u]      + b_hh[u];
  gf += b_ih[512+u]  + b_hh[512+u];
  gc += b_ih[1024+u] + b_hh[1024+u];
  go += b_ih[1536+u] + b_hh[1536+u];
  float cold = cbuf[(size_t)1*NB*CO + (size_t)b*CO + u];
  float cnew = sigmoidf_(gf)*cold + sigmoidf_(gi)*tanhf(gc);
  float hnew = sigmoidf_(go)*tanhf(cnew);
  out[(size_t)b*CO + u] = hnew;
}

// ===== diagnostic probes: run after final_k, touch only dead buffers =====

// gates body x16 (counters/time for the gates kernel)
__global__ __launch_bounds__(256) void pgates_k(
    const float* __restrict__ Wcat, const float* __restrict__ xhT,
    float* __restrict__ partT)
{
  __shared__ float tile[32][65];
  int s  = blockIdx.x & (NCHUNK-1);
  int rt = blockIdx.x >> 3;
  int wave = threadIdx.x >> 6, lane = threadIdx.x & 63;
  int r0 = rt*32 + wave*8;
  int c0 = s*CHUNK;
  #pragma unroll 1
  for (int rep=0; rep<16; rep++){
    const float* ap = xhT + (size_t)c0*NB + lane;
    const float* wp = Wcat + (size_t)c0*NGATES + r0;
    float acc[8];
    #pragma unroll
    for (int i=0;i<8;i++) acc[i]=0.f;
    #pragma unroll 4
    for (int k=0;k<CHUNK;k++){
      float a = ap[(size_t)k*NB];
      const float4* wr = (const float4*)(wp + (size_t)k*NGATES);
      float4 w0=wr[0], w1=wr[1];
      acc[0]+=w0.x*a; acc[1]+=w0.y*a; acc[2]+=w0.z*a; acc[3]+=w0.w*a;
      acc[4]+=w1.x*a; acc[5]+=w1.y*a; acc[6]+=w1.z*a; acc[7]+=w1.w*a;
    }
    __syncthreads();
    #pragma unroll
    for (int i=0;i<8;i++) tile[wave*8+i][lane] = acc[i];
    __syncthreads();
    int b = threadIdx.x >> 2, qq = threadIdx.x & 3;
    float* dst = partT + ((size_t)s*NB + b)*NGATES + rt*32 + qq*8;
    float4 v0, v1;
    v0.x=tile[qq*8+0][b]; v0.y=tile[qq*8+1][b]; v0.z=tile[qq*8+2][b]; v0.w=tile[qq*8+3][b];
    v1.x=tile[qq*8+4][b]; v1.y=tile[qq*8+5][b]; v1.z=tile[qq*8+6][b]; v1.w=tile[qq*8+7][b];
    *(float4*)dst = v0;
    *(float4*)(dst+4) = v1;
  }
}

// extlstm body xREPS, steady-state (t=2) path.
// V=0 exact; V=1 phase-1 via readlane (no LDS broadcast reads);
// V=2 img load hoisted; V=3 front-end only (skip phases 4-5).
template<int V, int REPS>
__global__ __launch_bounds__(512) void pext_k(
    const float* __restrict__ imgs,
    const float* __restrict__ partT,
    const float* __restrict__ b_ih, const float* __restrict__ b_hh,
    const float* __restrict__ Wg,   const float* __restrict__ bg,
    float* __restrict__ cbuf, float* __restrict__ xhT)
{
  __shared__ float hs[CO];
  __shared__ float gp[3];
  __shared__ float wred[8][4];
  __shared__ float prt[2][GS][4];
  __shared__ float rowinv[2][GS];
  __shared__ float fhT[256][20];
  __shared__ float fws[GS][260];
  __shared__ float g1[4][GS][260];
  __shared__ float g2[256][2];

  const int bc = blockIdx.x;
  const int b = bc/3, c = bc%3;
  const int t0 = threadIdx.x;
  const int q = t0>>6, lane = t0&63;

  #pragma unroll 1
  for (int rep=0; rep<REPS; rep++){
    // lstm (t>=2 path; reads cbuf[1]=c_15, real partT-shaped data)
    {
      const int u = t0;
      float gi=0.f,gf=0.f,gc=0.f,go=0.f;
      #pragma unroll
      for (int s2=0;s2<NCHUNK;s2++){
        const float* p = partT + ((size_t)s2*NB + b)*NGATES;
        gi += p[u]; gf += p[512+u]; gc += p[1024+u]; go += p[1536+u];
      }
      gi += b_ih[u]      + b_hh[u];
      gf += b_ih[512+u]  + b_hh[512+u];
      gc += b_ih[1024+u] + b_hh[1024+u];
      go += b_ih[1536+u] + b_hh[1536+u];
      float cold = cbuf[(size_t)1*NB*CO + (size_t)b*CO + u];
      float cnew = sigmoidf_(gf)*cold + sigmoidf_(gi)*tanhf(gc);
      float hnew = sigmoidf_(go)*tanhf(cnew);
      hs[u] = hnew;
      if (c == 0){
        cbuf[(size_t)0*NB*CO + (size_t)b*CO + u] = cnew;  // cbuf[0] dead
        xhT[(size_t)(INDIM+u)*NB + b] = hnew;              // dead
      }
    }
    __syncthreads();
    // params
    {
      float hval = hs[t0];
      float p0 = Wg[0*CO+t0]*hval;
      float p1 = Wg[1*CO+t0]*hval;
      float p2 = Wg[2*CO+t0]*hval;
      p0 = waveReduceSum(p0); p1 = waveReduceSum(p1); p2 = waveReduceSum(p2);
      if (lane==0){ wred[q][0]=p0; wred[q][1]=p1; wred[q][2]=p2; }
      __syncthreads();
      if (t0 < 3){
        float s = 0.f;
        #pragma unroll
        for (int w8=0; w8<8; w8++) s += wred[w8][t0];
        gp[t0] = tanhf(s + bg[t0]);
      }
      __syncthreads();
    }
    // filterbanks
    {
      float delta = gp[2];
      float dabs  = fabsf(delta);
      float deltas = ((float)IMG/(float)GS) * (1.0f - dabs);
      float gamma  = expf(1.0f - 2.0f*dabs);
      float inv_g  = 1.0f/gamma;
      float pref   = 1.0f/(3.14159265358979f*gamma);
      const int fb = t0 >> 8;
      const int p  = t0 & 255;
      const int wid = q & 3;
      float fi = (float)p;
      float fx[GS];
      float centers = 255.0f*0.5f*(gp[fb]+1.0f);
      #pragma unroll
      for (int g=0; g<GS; g++){
        float mu = centers + deltas*((float)g - 7.5f);
        float d  = (fi - mu)*inv_g;
        fx[g] = pref/(1.0f + d*d);
      }
      #pragma unroll
      for (int g=0; g<GS; g++){
        float sv = waveReduceSum(fx[g]);
        if (lane==0) prt[fb][g][wid]=sv;
      }
      __syncthreads();
      if (t0 < 32){
        int f2 = t0 >> 4, g = t0 & 15;
        rowinv[f2][g] = 1.0f/((((prt[f2][g][0]+prt[f2][g][1])+prt[f2][g][2])+prt[f2][g][3]) + EPSF);
      }
      __syncthreads();
      if (fb==0){
        #pragma unroll
        for (int g=0; g<GS; g++) fhT[p][g] = fx[g]*rowinv[0][g];
      } else {
        #pragma unroll
        for (int g=0; g<GS; g++) fws[g][p] = fx[g]*rowinv[1][g];
      }
      __syncthreads();
    }

    if constexpr (V == 3){
      // front-end only: tiny consumer so fb isn't DCE'd
      xhT[t0] = fhT[t0 & 255][0] + fws[t0 & 15][t0 & 255];
      __syncthreads();
      continue;
    }

    // phase 1
    {
      const float4* img4 = (const float4*)(imgs
          + (((size_t)b*2 + 0)*3 + c)*((size_t)IMG*IMG));
      float4 acc[GS];
      #pragma unroll
      for (int g=0; g<GS; g++){ acc[g].x=0.f; acc[g].y=0.f; acc[g].z=0.f; acc[g].w=0.f; }
      const int row0 = q*32;

      if constexpr (V == 1){
        // fh coefficients lane-distributed, broadcast via v_readlane (SALU)
        float4 vf0, vf1, vf2, vf3;
        {
          int r = row0 + (lane & 31);
          const float4* fq = (const float4*)&fhT[r][0];
          vf0=fq[0]; vf1=fq[1]; vf2=fq[2]; vf3=fq[3];
        }
        #pragma unroll 8
        for (int i=0; i<32; i++){
          const int row = row0 + i;
          float4 v = img4[(size_t)row*64 + lane];
          float f;
          f=RLF(vf0.x,i); FMA4(acc[0], f, v);
          f=RLF(vf0.y,i); FMA4(acc[1], f, v);
          f=RLF(vf0.z,i); FMA4(acc[2], f, v);
          f=RLF(vf0.w,i); FMA4(acc[3], f, v);
          f=RLF(vf1.x,i); FMA4(acc[4], f, v);
          f=RLF(vf1.y,i); FMA4(acc[5], f, v);
          f=RLF(vf1.z,i); FMA4(acc[6], f, v);
          f=RLF(vf1.w,i); FMA4(acc[7], f, v);
          f=RLF(vf2.x,i); FMA4(acc[8], f, v);
          f=RLF(vf2.y,i); FMA4(acc[9], f, v);
          f=RLF(vf2.z,i); FMA4(acc[10],f, v);
          f=RLF(vf2.w,i); FMA4(acc[11],f, v);
          f=RLF(vf3.x,i); FMA4(acc[12],f, v);
          f=RLF(vf3.y,i); FMA4(acc[13],f, v);
          f=RLF(vf3.z,i); FMA4(acc[14],f, v);
          f=RLF(vf3.w,i); FMA4(acc[15],f, v);
        }
      } else if constexpr (V == 2){
        // img load hoisted: one load, FMA/LDS identical
        float4 vc = img4[(size_t)row0*64 + lane];
        asm volatile("" : "+v"(vc.x), "+v"(vc.y), "+v"(vc.z), "+v"(vc.w));
        #pragma unroll 8
        for (int i=0; i<32; i++){
          const int row = row0 + i;
          float4 v = vc;
          const float4* fq = (const float4*)&fhT[row][0];
          float4 f0=fq[0], f1=fq[1], f2=fq[2], f3=fq[3];
          FMA4(acc[0], f0.x, v); FMA4(acc[1], f0.y, v); FMA4(acc[2], f0.z, v); FMA4(acc[3], f0.w, v);
          FMA4(acc[4], f1.x, v); FMA4(acc[5], f1.y, v); FMA4(acc[6], f1.z, v); FMA4(acc[7], f1.w, v);
          FMA4(acc[8], f2.x, v); FMA4(acc[9], f2.y, v); FMA4(acc[10],f2.z, v); FMA4(acc[11],f2.w, v);
          FMA4(acc[12],f3.x, v); FMA4(acc[13],f3.y, v); FMA4(acc[14],f3.z, v); FMA4(acc[15],f3.w, v);
        }
      } else {
        #pragma unroll 8
        for (int i=0; i<32; i++){
          const int row = row0 + i;
          float4 v = img4[(size_t)row*64 + lane];
          const float4* fq = (const float4*)&fhT[row][0];
          float4 f0=fq[0], f1=fq[1], f2=fq[2], f3=fq[3];
          FMA4(acc[0], f0.x, v); FMA4(acc[1], f0.y, v); FMA4(acc[2], f0.z, v); FMA4(acc[3], f0.w, v);
          FMA4(acc[4], f1.x, v); FMA4(acc[5], f1.y, v); FMA4(acc[6], f1.z, v); FMA4(acc[7], f1.w, v);
          FMA4(acc[8], f2.x, v); FMA4(acc[9], f2.y, v); FMA4(acc[10],f2.z, v); FMA4(acc[11],f2.w, v);
          FMA4(acc[12],f3.x, v); FMA4(acc[13],f3.y, v); FMA4(acc[14],f3.z, v); FMA4(acc[15],f3.w, v);
        }
      }

      if (q < 4){
        #pragma unroll
        for (int g=0; g<GS; g++) *(float4*)&g1[q][g][lane*4] = acc[g];
      }
      __syncthreads();
      if (q >= 4){
        #pragma unroll
        for (int g=0; g<GS; g++){
          float4 o = *(float4*)&g1[q-4][g][lane*4];
          o.x+=acc[g].x; o.y+=acc[g].y; o.z+=acc[g].z; o.w+=acc[g].w;
          *(float4*)&g1[q-4][g][lane*4] = o;
        }
      }
      __syncthreads();
      {
        #pragma unroll
        for (int gi2=0; gi2<2; gi2++){
          int g = q*2 + gi2;
          float4 s0 = *(float4*)&g1[0][g][lane*4];
          float4 s1 = *(float4*)&g1[1][g][lane*4];
          float4 s2 = *(float4*)&g1[2][g][lane*4];
          float4 s3 = *(float4*)&g1[3][g][lane*4];
          s0.x = ((s0.x+s1.x)+s2.x)+s3.x;
          s0.y = ((s0.y+s1.y)+s2.y)+s3.y;
          s0.z = ((s0.z+s1.z)+s2.z)+s3.z;
          s0.w = ((s0.w+s1.w)+s2.w)+s3.w;
          *(float4*)&g1[0][g][lane*4] = s0;
        }
      }
      __syncthreads();
    }
    // phase 2
    {
      int h2 = q >> 2;
      int o  = (q & 3)*64 + lane;
      int gg = o >> 4, kk = o & 15;
      const float4* grow = (const float4*)&g1[0][gg][h2*128];
      const float4* frow = (const float4*)&fws[kk][h2*128];
      float s = 0.f;
      #pragma unroll 8
      for (int j=0; j<32; j++){
        float4 gv = grow[j], fv = frow[j];
        s += gv.x*fv.x; s += gv.y*fv.y; s += gv.z*fv.z; s += gv.w*fv.w;
      }
      g2[o][h2] = s;
      __syncthreads();
      if (t0 < 256)
        xhT[(size_t)(c*256 + t0)*NB + b] = g2[t0][0] + g2[t0][1];  // dead
      __syncthreads();
    }
  }
}

extern "C" void kernel_launch(void* const* d_in, const int* in_sizes, int n_in,
                              void* d_out, int out_size, void* d_ws, size_t ws_size,
                              hipStream_t stream){
  const float* imgs = (const float*)d_in[0];
  const float* W_ih = (const float*)d_in[1];
  const float* W_hh = (const float*)d_in[2];
  const float* b_ih = (const float*)d_in[3];
  const float* b_hh = (const float*)d_in[4];
  const float* Wg   = (const float*)d_in[5];
  const float* bg   = (const float*)d_in[6];

  float* ws = (float*)d_ws;
  size_t off = 0;
  float* Wcat  = ws + off; off += (size_t)KTOT*NGATES;
  float* xhT   = ws + off; off += (size_t)KTOT*NB;
  float* partT = ws + off; off += (size_t)NCHUNK*NB*NGATES;
  float* cbuf  = ws + off; off += (size_t)2*NB*CO;
  float* outp  = (float*)d_out;

  transpose_k<<<dim3(INDIM/32, NGATES/32), dim3(32,8), 0, stream>>>(W_ih, Wcat, NGATES, INDIM);
  transpose_k<<<dim3(CO/32,    NGATES/32), dim3(32,8), 0, stream>>>(W_hh, Wcat + (size_t)INDIM*NGATES, NGATES, CO);

  for (int t=0; t<16; t++){
    extlstm4_k<<<NB*3, 512, 0, stream>>>(imgs, t, partT, b_ih, b_hh, Wg, bg, cbuf, xhT);
    gates5_k  <<<512,  256, 0, stream>>>(Wcat, xhT, partT);
  }
  final_k<<<NB, 512, 0, stream>>>(partT, b_ih, b_hh, cbuf, outp);

  // ---- diagnostic probes (after final_k; write only dead buffers) ----
  pgates_k        <<<512,  256, 0, stream>>>(Wcat, xhT, partT);
  pext_k<0,3>     <<<NB*3, 512, 0, stream>>>(imgs, partT, b_ih, b_hh, Wg, bg, cbuf, xhT);
  pext_k<1,3>     <<<NB*3, 512, 0, stream>>>(imgs, partT, b_ih, b_hh, Wg, bg, cbuf, xhT);
  pext_k<2,3>     <<<NB*3, 512, 0, stream>>>(imgs, partT, b_ih, b_hh, Wg, bg, cbuf, xhT);
  pext_k<3,8>     <<<NB*3, 512, 0, stream>>>(imgs, partT, b_ih, b_hh, Wg, bg, cbuf, xhT);
}

// Round 11
// 714.856 us; speedup vs baseline: 1.7164x; 1.7164x over previous
//
#include <hip/hip_runtime.h>
#include <math.h>

#define NB 64
#define CO 512
#define NGATES 2048
#define INDIM 768
#define KTOT 1280
#define IMG 256
#define GS 16
#define EPSF 1e-4f
#define NCHUNK 8
#define CHUNK 160   // KTOT / NCHUNK

#define FMA4(A,S,V) {(A).x+=(S)*(V).x;(A).y+=(S)*(V).y;(A).z+=(S)*(V).z;(A).w+=(S)*(V).w;}
#define RLF(x,i) __uint_as_float(__builtin_amdgcn_readlane(__float_as_uint(x),(i)))

__device__ __forceinline__ float sigmoidf_(float x){ return 1.0f/(1.0f+expf(-x)); }

__device__ __forceinline__ float waveReduceSum(float v){
  #pragma unroll
  for (int off=32; off>0; off>>=1) v += __shfl_down(v, off, 64);
  return v;
}

// out[c][r] = in[r][c]; rows, cols multiples of 32
__global__ __launch_bounds__(256) void transpose_k(const float* __restrict__ in,
                                                   float* __restrict__ out,
                                                   int rows, int cols){
  __shared__ float tile[32][33];
  int bx = blockIdx.x*32, by = blockIdx.y*32;
  int tx = threadIdx.x, ty = threadIdx.y;
  #pragma unroll
  for (int i=ty;i<32;i+=8)
    tile[i][tx] = in[(size_t)(by+i)*cols + bx+tx];
  __syncthreads();
  #pragma unroll
  for (int i=ty;i<32;i+=8)
    out[(size_t)(bx+i)*rows + by+tx] = tile[tx][i];
}

// Fused lstm + params + filterbanks + glimpse contraction.
// vs r8: phase-1 reads fh coeffs from LDS ONCE (4xb128 outside the loop),
// broadcasts in-loop via v_readlane -> no LDS ops in the hot loop, img
// loads pipeline freely. FP order bit-identical to r8.
__global__ __launch_bounds__(512) void extlstm6_k(
    const float* __restrict__ imgs,  // [NB][2][3][IMG][IMG]
    int t,                           // step 0..15
    const float* __restrict__ partT, // [NCHUNK][NB][NGATES] gates of step t-1
    const float* __restrict__ b_ih,  // [NGATES]
    const float* __restrict__ b_hh,  // [NGATES]
    const float* __restrict__ Wg,    // [3][CO]
    const float* __restrict__ bg,    // [3]
    float* __restrict__ cbuf,        // [2][NB][CO] ping-pong cell state
    float* __restrict__ xhT)         // [KTOT][NB]
{
  __shared__ float hs[CO];
  __shared__ float gp[3];
  __shared__ float wred[8][4];
  __shared__ float prt[2][GS][4];
  __shared__ float rowinv[2][GS];
  __shared__ float fhT[256][20];
  __shared__ float fws[GS][260];
  __shared__ float g1[4][GS][260];
  __shared__ float g2[256][2];

  const int bc = blockIdx.x;
  const int b = bc/3, c = bc%3;
  const int t0 = threadIdx.x;
  const int q = t0>>6, lane = t0&63;

  // ---- 1) h_t, c_t from previous step's gates ----
  if (t == 0){
    if (t0 < 256){ hs[t0]=0.f; hs[t0+256]=0.f; }
    if (c == 0) xhT[(size_t)(INDIM+t0)*NB + b] = 0.f;
  } else {
    const int u = t0;
    float gi=0.f,gf=0.f,gc=0.f,go=0.f;
    #pragma unroll
    for (int s2=0;s2<NCHUNK;s2++){
      const float* p = partT + ((size_t)s2*NB + b)*NGATES;
      gi += p[u]; gf += p[512+u]; gc += p[1024+u]; go += p[1536+u];
    }
    gi += b_ih[u]      + b_hh[u];
    gf += b_ih[512+u]  + b_hh[512+u];
    gc += b_ih[1024+u] + b_hh[1024+u];
    go += b_ih[1536+u] + b_hh[1536+u];
    float cold = (t==1) ? 0.f : cbuf[(size_t)((t-1)&1)*NB*CO + (size_t)b*CO + u];
    float cnew = sigmoidf_(gf)*cold + sigmoidf_(gi)*tanhf(gc);
    float hnew = sigmoidf_(go)*tanhf(cnew);
    hs[u] = hnew;
    if (c == 0){
      cbuf[(size_t)(t&1)*NB*CO + (size_t)b*CO + u] = cnew;
      xhT[(size_t)(INDIM+u)*NB + b] = hnew;
    }
  }
  __syncthreads();

  // ---- 2) glimpse params ----
  {
    float hval = hs[t0];
    float p0 = Wg[0*CO+t0]*hval;
    float p1 = Wg[1*CO+t0]*hval;
    float p2 = Wg[2*CO+t0]*hval;
    p0 = waveReduceSum(p0); p1 = waveReduceSum(p1); p2 = waveReduceSum(p2);
    if (lane==0){ wred[q][0]=p0; wred[q][1]=p1; wred[q][2]=p2; }
    __syncthreads();
    if (t0 < 3){
      float s = 0.f;
      #pragma unroll
      for (int w8=0; w8<8; w8++) s += wred[w8][t0];
      gp[t0] = tanhf(s + bg[t0]);
    }
    __syncthreads();
  }

  // ---- 3) filterbanks (parallel fb0/fb1) ----
  {
    float delta = gp[2];
    float dabs  = fabsf(delta);
    float deltas = ((float)IMG/(float)GS) * (1.0f - dabs);
    float gamma  = expf(1.0f - 2.0f*dabs);
    float inv_g  = 1.0f/gamma;
    float pref   = 1.0f/(3.14159265358979f*gamma);
    const int fb = t0 >> 8;
    const int p  = t0 & 255;
    const int wid = q & 3;
    float fi = (float)p;
    float fx[GS];
    float centers = 255.0f*0.5f*(gp[fb]+1.0f);
    #pragma unroll
    for (int g=0; g<GS; g++){
      float mu = centers + deltas*((float)g - 7.5f);
      float d  = (fi - mu)*inv_g;
      fx[g] = pref/(1.0f + d*d);
    }
    #pragma unroll
    for (int g=0; g<GS; g++){
      float sv = waveReduceSum(fx[g]);
      if (lane==0) prt[fb][g][wid]=sv;
    }
    __syncthreads();
    if (t0 < 32){
      int f2 = t0 >> 4, g = t0 & 15;
      rowinv[f2][g] = 1.0f/((((prt[f2][g][0]+prt[f2][g][1])+prt[f2][g][2])+prt[f2][g][3]) + EPSF);
    }
    __syncthreads();
    if (fb==0){
      #pragma unroll
      for (int g=0; g<GS; g++) fhT[p][g] = fx[g]*rowinv[0][g];
    } else {
      #pragma unroll
      for (int g=0; g<GS; g++) fws[g][p] = fx[g]*rowinv[1][g];
    }
    __syncthreads();
  }

  // ---- 4) phase 1: wave q owns hh [q*32,q*32+32); fh via readlane ----
  {
    const float4* img4 = (const float4*)(imgs
        + (((size_t)b*2 + (t&1))*3 + c)*((size_t)IMG*IMG));
    float4 acc[GS];
    #pragma unroll
    for (int g=0; g<GS; g++){ acc[g].x=0.f; acc[g].y=0.f; acc[g].z=0.f; acc[g].w=0.f; }
    const int row0 = q*32;
    // one-time LDS read: lane i (i<32) holds row (row0+i)'s 16 coefficients
    float4 vf0, vf1, vf2, vf3;
    {
      const float4* fq = (const float4*)&fhT[row0 + (lane & 31)][0];
      vf0=fq[0]; vf1=fq[1]; vf2=fq[2]; vf3=fq[3];
    }
    const float4* ip = img4 + (size_t)row0*64 + lane;
    #pragma unroll 8
    for (int i=0; i<32; i++){
      float4 v = ip[(size_t)i*64];                 // coalesced, pipelines deep
      float f;
      f=RLF(vf0.x,i); FMA4(acc[0], f, v);
      f=RLF(vf0.y,i); FMA4(acc[1], f, v);
      f=RLF(vf0.z,i); FMA4(acc[2], f, v);
      f=RLF(vf0.w,i); FMA4(acc[3], f, v);
      f=RLF(vf1.x,i); FMA4(acc[4], f, v);
      f=RLF(vf1.y,i); FMA4(acc[5], f, v);
      f=RLF(vf1.z,i); FMA4(acc[6], f, v);
      f=RLF(vf1.w,i); FMA4(acc[7], f, v);
      f=RLF(vf2.x,i); FMA4(acc[8], f, v);
      f=RLF(vf2.y,i); FMA4(acc[9], f, v);
      f=RLF(vf2.z,i); FMA4(acc[10],f, v);
      f=RLF(vf2.w,i); FMA4(acc[11],f, v);
      f=RLF(vf3.x,i); FMA4(acc[12],f, v);
      f=RLF(vf3.y,i); FMA4(acc[13],f, v);
      f=RLF(vf3.z,i); FMA4(acc[14],f, v);
      f=RLF(vf3.w,i); FMA4(acc[15],f, v);
    }
    // reduce 8 wave-partials -> 4 -> 1 (in g1[0]); FP order == r8
    if (q < 4){
      #pragma unroll
      for (int g=0; g<GS; g++) *(float4*)&g1[q][g][lane*4] = acc[g];
    }
    __syncthreads();
    if (q >= 4){
      #pragma unroll
      for (int g=0; g<GS; g++){
        float4 o = *(float4*)&g1[q-4][g][lane*4];
        o.x+=acc[g].x; o.y+=acc[g].y; o.z+=acc[g].z; o.w+=acc[g].w;
        *(float4*)&g1[q-4][g][lane*4] = o;
      }
    }
    __syncthreads();
    {
      #pragma unroll
      for (int gi2=0; gi2<2; gi2++){
        int g = q*2 + gi2;
        float4 s0 = *(float4*)&g1[0][g][lane*4];
        float4 s1 = *(float4*)&g1[1][g][lane*4];
        float4 s2 = *(float4*)&g1[2][g][lane*4];
        float4 s3 = *(float4*)&g1[3][g][lane*4];
        s0.x = ((s0.x+s1.x)+s2.x)+s3.x;
        s0.y = ((s0.y+s1.y)+s2.y)+s3.y;
        s0.z = ((s0.z+s1.z)+s2.z)+s3.z;
        s0.w = ((s0.w+s1.w)+s2.w)+s3.w;
        *(float4*)&g1[0][g][lane*4] = s0;
      }
    }
    __syncthreads();
  }

  // ---- 5) phase 2: h2 wave-uniform ----
  {
    int h2 = q >> 2;
    int o  = (q & 3)*64 + lane;
    int gg = o >> 4, kk = o & 15;
    const float4* grow = (const float4*)&g1[0][gg][h2*128];
    const float4* frow = (const float4*)&fws[kk][h2*128];
    float s = 0.f;
    #pragma unroll 8
    for (int j=0; j<32; j++){
      float4 gv = grow[j], fv = frow[j];
      s += gv.x*fv.x; s += gv.y*fv.y; s += gv.z*fv.z; s += gv.w*fv.w;
    }
    g2[o][h2] = s;
    __syncthreads();
    if (t0 < 256)
      xhT[(size_t)(c*256 + t0)*NB + b] = g2[t0][0] + g2[t0][1];
  }
}

// gates partial GEMM: partT[s][b][r] = sum_{k in chunk s} Wcat[k][r]*xhT[k][b]
// vs r8: pointer-increment addressing + explicit depth-4 register pipeline
// (12 loads in flight). Accumulation order over k unchanged (sequential).
__global__ __launch_bounds__(256) void gates7_k(
    const float* __restrict__ Wcat,  // [KTOT][NGATES]
    const float* __restrict__ xhT,   // [KTOT][NB]
    float* __restrict__ partT)       // [NCHUNK][NB][NGATES]
{
  __shared__ float tile[32][65];
  int s  = blockIdx.x & (NCHUNK-1);
  int rt = blockIdx.x >> 3;
  int wave = threadIdx.x >> 6, lane = threadIdx.x & 63;
  int r0 = rt*32 + wave*8;
  int c0 = s*CHUNK;
  const float* ap = xhT + (size_t)c0*NB + lane;
  const float* wp = Wcat + (size_t)c0*NGATES + r0;
  float acc[8];
  #pragma unroll
  for (int i=0;i<8;i++) acc[i]=0.f;

  float4 sw0[4], sw1[4];
  float  sa[4];
  #pragma unroll
  for (int j=0;j<4;j++){
    sw0[j] = *(const float4*)(wp);
    sw1[j] = *(const float4*)(wp+4);
    sa[j]  = *ap;
    wp += NGATES; ap += NB;
  }
  #pragma unroll 1
  for (int i=0; i<39; i++){
    #pragma unroll
    for (int j=0;j<4;j++){
      float4 cw0=sw0[j], cw1=sw1[j]; float ca=sa[j];
      sw0[j] = *(const float4*)(wp);
      sw1[j] = *(const float4*)(wp+4);
      sa[j]  = *ap;
      wp += NGATES; ap += NB;
      acc[0]+=cw0.x*ca; acc[1]+=cw0.y*ca; acc[2]+=cw0.z*ca; acc[3]+=cw0.w*ca;
      acc[4]+=cw1.x*ca; acc[5]+=cw1.y*ca; acc[6]+=cw1.z*ca; acc[7]+=cw1.w*ca;
    }
  }
  #pragma unroll
  for (int j=0;j<4;j++){
    float4 cw0=sw0[j], cw1=sw1[j]; float ca=sa[j];
    acc[0]+=cw0.x*ca; acc[1]+=cw0.y*ca; acc[2]+=cw0.z*ca; acc[3]+=cw0.w*ca;
    acc[4]+=cw1.x*ca; acc[5]+=cw1.y*ca; acc[6]+=cw1.z*ca; acc[7]+=cw1.w*ca;
  }

  #pragma unroll
  for (int i=0;i<8;i++) tile[wave*8+i][lane] = acc[i];
  __syncthreads();
  int b = threadIdx.x >> 2, qq = threadIdx.x & 3;
  float* dst = partT + ((size_t)s*NB + b)*NGATES + rt*32 + qq*8;
  float4 v0, v1;
  v0.x=tile[qq*8+0][b]; v0.y=tile[qq*8+1][b]; v0.z=tile[qq*8+2][b]; v0.w=tile[qq*8+3][b];
  v1.x=tile[qq*8+4][b]; v1.y=tile[qq*8+5][b]; v1.z=tile[qq*8+6][b]; v1.w=tile[qq*8+7][b];
  *(float4*)dst = v0;
  *(float4*)(dst+4) = v1;
}

// final LSTM (step 15's gates) -> h_16 to d_out. Block per b, thread = u.
__global__ __launch_bounds__(512) void final_k(
    const float* __restrict__ partT,
    const float* __restrict__ b_ih, const float* __restrict__ b_hh,
    const float* __restrict__ cbuf, float* __restrict__ out)
{
  int b = blockIdx.x, u = threadIdx.x;
  float gi=0.f, gf=0.f, gc=0.f, go=0.f;
  #pragma unroll
  for (int s2=0; s2<NCHUNK; s2++){
    const float* p = partT + ((size_t)s2*NB + b)*NGATES;
    gi += p[u]; gf += p[512+u]; gc += p[1024+u]; go += p[1536+u];
  }
  gi += b_ih[u]      + b_hh[u];
  gf += b_ih[512+u]  + b_hh[512+u];
  gc += b_ih[1024+u] + b_hh[1024+u];
  go += b_ih[1536+u] + b_hh[1536+u];
  float cold = cbuf[(size_t)1*NB*CO + (size_t)b*CO + u];
  float cnew = sigmoidf_(gf)*cold + sigmoidf_(gi)*tanhf(gc);
  float hnew = sigmoidf_(go)*tanhf(cnew);
  out[(size_t)b*CO + u] = hnew;
}

extern "C" void kernel_launch(void* const* d_in, const int* in_sizes, int n_in,
                              void* d_out, int out_size, void* d_ws, size_t ws_size,
                              hipStream_t stream){
  const float* imgs = (const float*)d_in[0];
  const float* W_ih = (const float*)d_in[1];
  const float* W_hh = (const float*)d_in[2];
  const float* b_ih = (const float*)d_in[3];
  const float* b_hh = (const float*)d_in[4];
  const float* Wg   = (const float*)d_in[5];
  const float* bg   = (const float*)d_in[6];
  // d_in[7] = num_glimpses (always 8) -> 16 steps hardcoded.

  float* ws = (float*)d_ws;
  size_t off = 0;
  float* Wcat  = ws + off; off += (size_t)KTOT*NGATES;
  float* xhT   = ws + off; off += (size_t)KTOT*NB;
  float* partT = ws + off; off += (size_t)NCHUNK*NB*NGATES;
  float* cbuf  = ws + off; off += (size_t)2*NB*CO;
  float* outp  = (float*)d_out;

  transpose_k<<<dim3(INDIM/32, NGATES/32), dim3(32,8), 0, stream>>>(W_ih, Wcat, NGATES, INDIM);
  transpose_k<<<dim3(CO/32,    NGATES/32), dim3(32,8), 0, stream>>>(W_hh, Wcat + (size_t)INDIM*NGATES, NGATES, CO);

  for (int t=0; t<16; t++){
    extlstm6_k<<<NB*3, 512, 0, stream>>>(imgs, t, partT, b_ih, b_hh, Wg, bg, cbuf, xhT);
    gates7_k  <<<512,  256, 0, stream>>>(Wcat, xhT, partT);
  }
  final_k<<<NB, 512, 0, stream>>>(partT, b_ih, b_hh, cbuf, outp);
}

// Round 12
// 522.639 us; speedup vs baseline: 2.3477x; 1.3678x over previous
//
#include <hip/hip_runtime.h>
#include <math.h>

#define NB 64
#define CO 512
#define NGATES 2048
#define INDIM 768
#define KTOT 1280
#define IMG 256
#define GS 16
#define EPSF 1e-4f
#define NCHUNK 8
#define CHUNK 160   // KTOT / NCHUNK

#define FMA4(A,S,V) {(A).x+=(S)*(V).x;(A).y+=(S)*(V).y;(A).z+=(S)*(V).z;(A).w+=(S)*(V).w;}

__device__ __forceinline__ float sigmoidf_(float x){ return 1.0f/(1.0f+expf(-x)); }

__device__ __forceinline__ float waveReduceSum(float v){
  #pragma unroll
  for (int off=32; off>0; off>>=1) v += __shfl_down(v, off, 64);
  return v;
}

// out[c][r] = in[r][c]; rows, cols multiples of 32
__global__ __launch_bounds__(256) void transpose_k(const float* __restrict__ in,
                                                   float* __restrict__ out,
                                                   int rows, int cols){
  __shared__ float tile[32][33];
  int bx = blockIdx.x*32, by = blockIdx.y*32;
  int tx = threadIdx.x, ty = threadIdx.y;
  #pragma unroll
  for (int i=ty;i<32;i+=8)
    tile[i][tx] = in[(size_t)(by+i)*cols + bx+tx];
  __syncthreads();
  #pragma unroll
  for (int i=ty;i<32;i+=8)
    out[(size_t)(bx+i)*rows + by+tx] = tile[tx][i];
}

// ===== extlstm4_k: r8 verbatim (known-good 702us config) =====
__global__ __launch_bounds__(512) void extlstm4_k(
    const float* __restrict__ imgs, int t,
    const float* __restrict__ partT,
    const float* __restrict__ b_ih, const float* __restrict__ b_hh,
    const float* __restrict__ Wg,   const float* __restrict__ bg,
    float* __restrict__ cbuf, float* __restrict__ xhT)
{
  __shared__ float hs[CO];
  __shared__ float gp[3];
  __shared__ float wred[8][4];
  __shared__ float prt[2][GS][4];
  __shared__ float rowinv[2][GS];
  __shared__ float fhT[256][20];
  __shared__ float fws[GS][260];
  __shared__ float g1[4][GS][260];
  __shared__ float g2[256][2];

  const int bc = blockIdx.x;
  const int b = bc/3, c = bc%3;
  const int t0 = threadIdx.x;
  const int q = t0>>6, lane = t0&63;

  if (t == 0){
    if (t0 < 256){ hs[t0]=0.f; hs[t0+256]=0.f; }
    if (c == 0) xhT[(size_t)(INDIM+t0)*NB + b] = 0.f;
  } else {
    const int u = t0;
    float gi=0.f,gf=0.f,gc=0.f,go=0.f;
    #pragma unroll
    for (int s2=0;s2<NCHUNK;s2++){
      const float* p = partT + ((size_t)s2*NB + b)*NGATES;
      gi += p[u]; gf += p[512+u]; gc += p[1024+u]; go += p[1536+u];
    }
    gi += b_ih[u]      + b_hh[u];
    gf += b_ih[512+u]  + b_hh[512+u];
    gc += b_ih[1024+u] + b_hh[1024+u];
    go += b_ih[1536+u] + b_hh[1536+u];
    float cold = (t==1) ? 0.f : cbuf[(size_t)((t-1)&1)*NB*CO + (size_t)b*CO + u];
    float cnew = sigmoidf_(gf)*cold + sigmoidf_(gi)*tanhf(gc);
    float hnew = sigmoidf_(go)*tanhf(cnew);
    hs[u] = hnew;
    if (c == 0){
      cbuf[(size_t)(t&1)*NB*CO + (size_t)b*CO + u] = cnew;
      xhT[(size_t)(INDIM+u)*NB + b] = hnew;
    }
  }
  __syncthreads();

  {
    float hval = hs[t0];
    float p0 = Wg[0*CO+t0]*hval;
    float p1 = Wg[1*CO+t0]*hval;
    float p2 = Wg[2*CO+t0]*hval;
    p0 = waveReduceSum(p0); p1 = waveReduceSum(p1); p2 = waveReduceSum(p2);
    if (lane==0){ wred[q][0]=p0; wred[q][1]=p1; wred[q][2]=p2; }
    __syncthreads();
    if (t0 < 3){
      float s = 0.f;
      #pragma unroll
      for (int w8=0; w8<8; w8++) s += wred[w8][t0];
      gp[t0] = tanhf(s + bg[t0]);
    }
    __syncthreads();
  }

  {
    float delta = gp[2];
    float dabs  = fabsf(delta);
    float deltas = ((float)IMG/(float)GS) * (1.0f - dabs);
    float gamma  = expf(1.0f - 2.0f*dabs);
    float inv_g  = 1.0f/gamma;
    float pref   = 1.0f/(3.14159265358979f*gamma);
    const int fb = t0 >> 8;
    const int p  = t0 & 255;
    const int wid = q & 3;
    float fi = (float)p;
    float fx[GS];
    float centers = 255.0f*0.5f*(gp[fb]+1.0f);
    #pragma unroll
    for (int g=0; g<GS; g++){
      float mu = centers + deltas*((float)g - 7.5f);
      float d  = (fi - mu)*inv_g;
      fx[g] = pref/(1.0f + d*d);
    }
    #pragma unroll
    for (int g=0; g<GS; g++){
      float sv = waveReduceSum(fx[g]);
      if (lane==0) prt[fb][g][wid]=sv;
    }
    __syncthreads();
    if (t0 < 32){
      int f2 = t0 >> 4, g = t0 & 15;
      rowinv[f2][g] = 1.0f/((((prt[f2][g][0]+prt[f2][g][1])+prt[f2][g][2])+prt[f2][g][3]) + EPSF);
    }
    __syncthreads();
    if (fb==0){
      #pragma unroll
      for (int g=0; g<GS; g++) fhT[p][g] = fx[g]*rowinv[0][g];
    } else {
      #pragma unroll
      for (int g=0; g<GS; g++) fws[g][p] = fx[g]*rowinv[1][g];
    }
    __syncthreads();
  }

  {
    const float4* img4 = (const float4*)(imgs
        + (((size_t)b*2 + (t&1))*3 + c)*((size_t)IMG*IMG));
    float4 acc[GS];
    #pragma unroll
    for (int g=0; g<GS; g++){ acc[g].x=0.f; acc[g].y=0.f; acc[g].z=0.f; acc[g].w=0.f; }
    const int row0 = q*32;
    #pragma unroll 8
    for (int i=0; i<32; i++){
      const int row = row0 + i;
      float4 v = img4[(size_t)row*64 + lane];
      const float4* fq = (const float4*)&fhT[row][0];
      float4 f0=fq[0], f1=fq[1], f2=fq[2], f3=fq[3];
      FMA4(acc[0], f0.x, v); FMA4(acc[1], f0.y, v); FMA4(acc[2], f0.z, v); FMA4(acc[3], f0.w, v);
      FMA4(acc[4], f1.x, v); FMA4(acc[5], f1.y, v); FMA4(acc[6], f1.z, v); FMA4(acc[7], f1.w, v);
      FMA4(acc[8], f2.x, v); FMA4(acc[9], f2.y, v); FMA4(acc[10],f2.z, v); FMA4(acc[11],f2.w, v);
      FMA4(acc[12],f3.x, v); FMA4(acc[13],f3.y, v); FMA4(acc[14],f3.z, v); FMA4(acc[15],f3.w, v);
    }
    if (q < 4){
      #pragma unroll
      for (int g=0; g<GS; g++) *(float4*)&g1[q][g][lane*4] = acc[g];
    }
    __syncthreads();
    if (q >= 4){
      #pragma unroll
      for (int g=0; g<GS; g++){
        float4 o = *(float4*)&g1[q-4][g][lane*4];
        o.x+=acc[g].x; o.y+=acc[g].y; o.z+=acc[g].z; o.w+=acc[g].w;
        *(float4*)&g1[q-4][g][lane*4] = o;
      }
    }
    __syncthreads();
    {
      #pragma unroll
      for (int gi2=0; gi2<2; gi2++){
        int g = q*2 + gi2;
        float4 s0 = *(float4*)&g1[0][g][lane*4];
        float4 s1 = *(float4*)&g1[1][g][lane*4];
        float4 s2 = *(float4*)&g1[2][g][lane*4];
        float4 s3 = *(float4*)&g1[3][g][lane*4];
        s0.x = ((s0.x+s1.x)+s2.x)+s3.x;
        s0.y = ((s0.y+s1.y)+s2.y)+s3.y;
        s0.z = ((s0.z+s1.z)+s2.z)+s3.z;
        s0.w = ((s0.w+s1.w)+s2.w)+s3.w;
        *(float4*)&g1[0][g][lane*4] = s0;
      }
    }
    __syncthreads();
  }

  {
    int h2 = q >> 2;
    int o  = (q & 3)*64 + lane;
    int gg = o >> 4, kk = o & 15;
    const float4* grow = (const float4*)&g1[0][gg][h2*128];
    const float4* frow = (const float4*)&fws[kk][h2*128];
    float s = 0.f;
    #pragma unroll 8
    for (int j=0; j<32; j++){
      float4 gv = grow[j], fv = frow[j];
      s += gv.x*fv.x; s += gv.y*fv.y; s += gv.z*fv.z; s += gv.w*fv.w;
    }
    g2[o][h2] = s;
    __syncthreads();
    if (t0 < 256)
      xhT[(size_t)(c*256 + t0)*NB + b] = g2[t0][0] + g2[t0][1];
  }
}

// gates8: LDS-staged partial GEMM. Block = (chunk s, 32-row tile rt).
// Stage W[160][32] (20KB, coalesced segments) + xh[160][64] (40KB, contiguous)
// into LDS, then pure-LDS inner loop: thread = 4 rows x 2 batches.
// Per-output k-accumulation order identical to gates5 -> bit-identical partT.
__global__ __launch_bounds__(256) void gates8_k(
    const float* __restrict__ Wcat,  // [KTOT][NGATES]
    const float* __restrict__ xhT,   // [KTOT][NB]
    float* __restrict__ partT)       // [NCHUNK][NB][NGATES]
{
  __shared__ float Wlds[CHUNK][32];   // 20 KB
  __shared__ float xhl[CHUNK][NB];    // 40 KB; reused as transpose tile after
  const int s  = blockIdx.x & (NCHUNK-1);
  const int rt = blockIdx.x >> 3;
  const int r0 = rt*32;
  const int c0 = s*CHUNK;
  const int t  = threadIdx.x;

  // ---- stage ----
  {
    const float* wsrc = Wcat + (size_t)c0*NGATES + r0;
    const int f4 = t & 7, kk = t >> 3;          // kk 0..31
    #pragma unroll
    for (int p=0; p<5; p++){
      const int k = kk + p*32;
      *(float4*)&Wlds[k][f4*4] =
          *(const float4*)(wsrc + (size_t)k*NGATES + f4*4);
    }
    const float4* xsrc = (const float4*)(xhT + (size_t)c0*NB);
    float4* xdst = (float4*)&xhl[0][0];
    #pragma unroll
    for (int p=0; p<10; p++)
      xdst[t + p*256] = xsrc[t + p*256];
  }
  __syncthreads();

  // ---- compute: thread -> rows r0+4*r4.., batches 2*bp.. ----
  const int r4 = t & 7, bp = t >> 3;
  float a00=0.f,a01=0.f,a10=0.f,a11=0.f,a20=0.f,a21=0.f,a30=0.f,a31=0.f;
  #pragma unroll 8
  for (int k=0; k<CHUNK; k++){
    float4 w = *(const float4*)&Wlds[k][r4*4];
    float2 x = *(const float2*)&xhl[k][bp*2];
    a00+=w.x*x.x; a01+=w.x*x.y;
    a10+=w.y*x.x; a11+=w.y*x.y;
    a20+=w.z*x.x; a21+=w.z*x.y;
    a30+=w.w*x.x; a31+=w.w*x.y;
  }
  __syncthreads();

  // ---- epilogue: transpose via LDS (reuse xhl as tile[32][65]) ----
  float* tile = &xhl[0][0];
  const int rl = r4*4, bb = bp*2;
  tile[(rl+0)*65 + bb] = a00; tile[(rl+0)*65 + bb+1] = a01;
  tile[(rl+1)*65 + bb] = a10; tile[(rl+1)*65 + bb+1] = a11;
  tile[(rl+2)*65 + bb] = a20; tile[(rl+2)*65 + bb+1] = a21;
  tile[(rl+3)*65 + bb] = a30; tile[(rl+3)*65 + bb+1] = a31;
  __syncthreads();
  const int b = t >> 2, qq = t & 3;
  float* dst = partT + ((size_t)s*NB + b)*NGATES + r0 + qq*8;
  float4 v0, v1;
  v0.x=tile[(qq*8+0)*65+b]; v0.y=tile[(qq*8+1)*65+b];
  v0.z=tile[(qq*8+2)*65+b]; v0.w=tile[(qq*8+3)*65+b];
  v1.x=tile[(qq*8+4)*65+b]; v1.y=tile[(qq*8+5)*65+b];
  v1.z=tile[(qq*8+6)*65+b]; v1.w=tile[(qq*8+7)*65+b];
  *(float4*)dst = v0;
  *(float4*)(dst+4) = v1;
}

// final LSTM (step 15's gates) -> h_16 to d_out. Block per b, thread = u.
__global__ __launch_bounds__(512) void final_k(
    const float* __restrict__ partT,
    const float* __restrict__ b_ih, const float* __restrict__ b_hh,
    const float* __restrict__ cbuf, float* __restrict__ out)
{
  int b = blockIdx.x, u = threadIdx.x;
  float gi=0.f, gf=0.f, gc=0.f, go=0.f;
  #pragma unroll
  for (int s2=0; s2<NCHUNK; s2++){
    const float* p = partT + ((size_t)s2*NB + b)*NGATES;
    gi += p[u]; gf += p[512+u]; gc += p[1024+u]; go += p[1536+u];
  }
  gi += b_ih[u]      + b_hh[u];
  gf += b_ih[512+u]  + b_hh[512+u];
  gc += b_ih[1024+u] + b_hh[1024+u];
  go += b_ih[1536+u] + b_hh[1536+u];
  float cold = cbuf[(size_t)1*NB*CO + (size_t)b*CO + u];
  float cnew = sigmoidf_(gf)*cold + sigmoidf_(gi)*tanhf(gc);
  float hnew = sigmoidf_(go)*tanhf(cnew);
  out[(size_t)b*CO + u] = hnew;
}

extern "C" void kernel_launch(void* const* d_in, const int* in_sizes, int n_in,
                              void* d_out, int out_size, void* d_ws, size_t ws_size,
                              hipStream_t stream){
  const float* imgs = (const float*)d_in[0];
  const float* W_ih = (const float*)d_in[1];
  const float* W_hh = (const float*)d_in[2];
  const float* b_ih = (const float*)d_in[3];
  const float* b_hh = (const float*)d_in[4];
  const float* Wg   = (const float*)d_in[5];
  const float* bg   = (const float*)d_in[6];
  // d_in[7] = num_glimpses (always 8) -> 16 steps hardcoded.

  float* ws = (float*)d_ws;
  size_t off = 0;
  float* Wcat  = ws + off; off += (size_t)KTOT*NGATES;
  float* xhT   = ws + off; off += (size_t)KTOT*NB;
  float* partT = ws + off; off += (size_t)NCHUNK*NB*NGATES;
  float* cbuf  = ws + off; off += (size_t)2*NB*CO;
  float* outp  = (float*)d_out;

  transpose_k<<<dim3(INDIM/32, NGATES/32), dim3(32,8), 0, stream>>>(W_ih, Wcat, NGATES, INDIM);
  transpose_k<<<dim3(CO/32,    NGATES/32), dim3(32,8), 0, stream>>>(W_hh, Wcat + (size_t)INDIM*NGATES, NGATES, CO);

  for (int t=0; t<16; t++){
    extlstm4_k<<<NB*3, 512, 0, stream>>>(imgs, t, partT, b_ih, b_hh, Wg, bg, cbuf, xhT);
    gates8_k  <<<512,  256, 0, stream>>>(Wcat, xhT, partT);
  }
  final_k<<<NB, 512, 0, stream>>>(partT, b_ih, b_hh, cbuf, outp);
}